// Round 3
// baseline (8874.983 us; speedup 1.0000x reference)
//
#include <hip/hip_runtime.h>
#include <hip/hip_bf16.h>
#include <stdint.h>

#define TT 1024
#define BB 32
#define DD 1024

typedef __attribute__((ext_vector_type(8))) short short8;
typedef __attribute__((ext_vector_type(4))) unsigned short ushort4v;
typedef __attribute__((ext_vector_type(4))) float floatx4;
typedef __attribute__((ext_vector_type(2))) unsigned long long ull2;

static __device__ __forceinline__ unsigned short f2bf(float f){
  unsigned u = __float_as_uint(f);
  u += 0x7fffu + ((u >> 16) & 1u);   // RNE
  return (unsigned short)(u >> 16);
}
static __device__ __forceinline__ float bf2f(unsigned short s){
  return __uint_as_float(((unsigned)s) << 16);
}
static __device__ __forceinline__ float sigm(float x){
  return __fdividef(1.0f, 1.0f + __expf(-x));
}
static __device__ __forceinline__ float fast_tanh(float x){
  float e = __expf(2.0f * x);
  return 1.0f - __fdividef(2.0f, e + 1.0f);
}

// ---------------- workspace layout (bytes) ----------------
// frag: [t][bh(2)][nt(128)][lane(64)][4] bf16; nt 0..63 alpha preact, 64..127 wx.
// h_{t+1} is stored (via L2-bypassing relaxed agent atomics) into the DEAD alpha
// half of frag[t-1]; h_t is read from frag[t-2]'s alpha half (also via atomics).
#define WS_FRAG_BYTES (134217728ull)                 // 1024*2*128*64*4*2
#define WS_WCAT_OFF   (WS_FRAG_BYTES)
#define WS_WCAT_BYTES (4194304ull)                   // 2048*1024*2 bf16 [Walpha;Wx]
#define WS_HINIT_OFF  (WS_WCAT_OFF + WS_WCAT_BYTES)  // 32*1024 bf16 h0
#define WS_H1_OFF     (WS_HINIT_OFF + 65536ull)      // 32*1024 bf16 h1
#define WS_FLAG_OFF   (WS_H1_OFF + 65536ull)         // 32 flags, 128B apart

// ---------------- init: cast weights, seed h0 bf16, write hout[0], zero flags
__global__ void init_kernel(const float* __restrict__ Wa, const float* __restrict__ Wx,
                            const float* __restrict__ h0, float* __restrict__ hout0,
                            unsigned short* __restrict__ Wcat,
                            unsigned short* __restrict__ hinit,
                            unsigned* __restrict__ flags)
{
  long i = (long)blockIdx.x * 256 + threadIdx.x;
  if (blockIdx.x == 0 && threadIdx.x < 32)
    __hip_atomic_store(&flags[threadIdx.x * 32], 0u, __ATOMIC_RELAXED, __HIP_MEMORY_SCOPE_AGENT);
  const long NW = 2048L * 1024L;
  for (long idx = i; idx < NW; idx += (long)gridDim.x * 256L){
    long r = idx >> 10, c = idx & 1023;
    float v = (r < 1024) ? Wa[r*1024 + c] : Wx[(r-1024)*1024 + c];
    Wcat[idx] = f2bf(v);
  }
  const long NH = 32L * 1024L;
  for (long idx = i; idx < NH; idx += (long)gridDim.x * 256L){
    float v = h0[idx];
    hinit[idx] = f2bf(v);
    hout0[idx] = v;          // hout[0] = h0 (fp32)
  }
}

// ---------------- precompute GEMM: [alpha_preact | wx] for all (t,b), bf16 MFMA-fragment layout
__global__ __launch_bounds__(256) void pre_gemm(
    const float* __restrict__ x, const unsigned short* __restrict__ Wcat,
    const float* __restrict__ b_alpha, const float* __restrict__ b_x,
    unsigned short* __restrict__ frag)
{
  __shared__ unsigned short A_lds[128*72];
  __shared__ unsigned short B_lds[128*72];
  const int tid = threadIdx.x;
  const int lane = tid & 63;
  const int w = tid >> 6;
  const int wm = w >> 1, wn = w & 1;
  const long m0 = (long)blockIdx.y * 128;
  const int n0 = blockIdx.x * 128;

  floatx4 acc[4][4];
#pragma unroll
  for (int i=0;i<4;++i)
#pragma unroll
    for (int j=0;j<4;++j) acc[i][j] = (floatx4){0.f,0.f,0.f,0.f};

  for (int kt=0; kt<16; ++kt){
    const int k0 = kt*64;
    __syncthreads();
#pragma unroll
    for (int rep=0; rep<4; ++rep){
      int flat = rep*2048 + tid*8;
      int r = flat >> 6, c = flat & 63;
      const float* src = &x[(m0 + r)*1024 + k0 + c];
      floatx4 f0 = *(const floatx4*)src;
      floatx4 f1 = *(const floatx4*)(src + 4);
      short8 v;
      v[0]=(short)f2bf(f0[0]); v[1]=(short)f2bf(f0[1]); v[2]=(short)f2bf(f0[2]); v[3]=(short)f2bf(f0[3]);
      v[4]=(short)f2bf(f1[0]); v[5]=(short)f2bf(f1[1]); v[6]=(short)f2bf(f1[2]); v[7]=(short)f2bf(f1[3]);
      *(short8*)&A_lds[r*72 + c] = v;
      short8 bv = *(const short8*)&Wcat[(long)(n0 + r)*1024 + k0 + c];
      *(short8*)&B_lds[r*72 + c] = bv;
    }
    __syncthreads();
#pragma unroll
    for (int kb=0; kb<2; ++kb){
      short8 a[4], b[4];
#pragma unroll
      for (int f=0; f<4; ++f)
        a[f] = *(const short8*)&A_lds[(wm*64 + f*16 + (lane&15))*72 + kb*32 + (lane>>4)*8];
#pragma unroll
      for (int f=0; f<4; ++f)
        b[f] = *(const short8*)&B_lds[(wn*64 + f*16 + (lane&15))*72 + kb*32 + (lane>>4)*8];
#pragma unroll
      for (int fm=0; fm<4; ++fm)
#pragma unroll
        for (int fn=0; fn<4; ++fn)
          acc[fm][fn] = __builtin_amdgcn_mfma_f32_16x16x32_bf16(a[fm], b[fn], acc[fm][fn], 0, 0, 0);
    }
  }

#pragma unroll
  for (int fm=0; fm<4; ++fm){
    const long mrow = m0 + wm*64 + fm*16;
    const int t  = (int)(mrow >> 5);
    const int bh = (int)((mrow >> 4) & 1);
#pragma unroll
    for (int fn=0; fn<4; ++fn){
      const int nf  = n0 + wn*64 + fn*16;
      const int nt  = nf >> 4;
      const int col = nf + (lane & 15);
      floatx4 v = acc[fm][fn];
      const float bias = (col < DD) ? b_alpha[col] : b_x[col - DD];
      ushort4v o;
#pragma unroll
      for (int i=0;i<4;++i) o[i] = f2bf(v[i] + bias);
      *(ushort4v*)&frag[((((long)t*2 + bh)*128 + nt)*64 + lane)*4] = o;
    }
  }
}

// ---------------- sequential scan (32 wgs = 2 groups x 16 slices)
// Cross-wg traffic uses ONLY relaxed agent-scope atomics (sc1: bypass per-XCD L2,
// served by MALL) -> no buffer_wbl2 / buffer_inv per step. Ordering: __syncthreads
// drains vmcnt (stores acked at MALL) before the relaxed flag store.
__global__ __launch_bounds__(256, 1) void scan_kernel(
    const float* __restrict__ Wh, const float* __restrict__ h0,
    unsigned short* frag,                  // also h storage (dead alpha halves)
    const unsigned short* __restrict__ hinit,
    unsigned short* h1buf,
    unsigned* flags)
{
  __shared__ unsigned short W_lds[64*1024];  // XOR-swizzled, stride 1024
  __shared__ unsigned short tile[16*72];     // per-step h transpose staging
  const int tid  = threadIdx.x;
  const int lane = tid & 63;
  const int w    = tid >> 6;
  const int bh   = blockIdx.x & 1;
  const int wsld = blockIdx.x >> 1;     // 0..15 weight slice
  const int base_r = wsld * 64;

  // one-time: W_h slice fp32 -> bf16 LDS, 16B-granule XOR swizzle (G4 recipe):
  // element (r,c) stored at r*1024 + (c ^ ((r&7)*8))  [shorts]
  for (int it=0; it<64; ++it){
    const int r = it, c = tid*4;
    floatx4 f = *(const floatx4*)&Wh[(long)(base_r + r)*1024 + c];
    ushort4v v;
    v[0]=f2bf(f[0]); v[1]=f2bf(f[1]); v[2]=f2bf(f[2]); v[3]=f2bf(f[3]);
    *(ushort4v*)&W_lds[r*1024 + (c ^ ((r&7)*8))] = v;
  }

  const int n0   = base_r + w*16;
  const int colf = n0 + (lane & 15);
  const int nt_a = n0 >> 4;
  float hp[4];
#pragma unroll
  for (int i=0;i<4;++i){
    int gb = bh*16 + (lane>>4)*4 + i;
    hp[i] = h0[(long)gb*1024 + colf];
  }
  __syncthreads();

  unsigned* myflag   = flags + (bh*16 + wsld)*32;
  unsigned* grpflags = flags + bh*16*32;
  const int hrow = lane & 15;
  const int g8   = (lane >> 4) * 8;
  const int brow = w*16 + (lane & 15);
  const int boff0 = g8 ^ ((brow & 7) * 8);
  const unsigned short* Wrow = &W_lds[brow * 1024];

  // preload frag for t=0 (plain loads: wx/alpha halves written only by pre_gemm)
  long fb = (((long)0*2 + bh)*128 + nt_a)*64 + lane;
  ushort4v al = *(const ushort4v*)&frag[fb*4];
  ushort4v wx = *(const ushort4v*)&frag[(fb + 64*64)*4];

  for (int t=0; t<TT; ++t){
    if (t > 0){
      const unsigned tgt = (unsigned)t;
      bool ok;
      do {
        unsigned v = __hip_atomic_load(&grpflags[(lane & 15)*32],
                                       __ATOMIC_RELAXED, __HIP_MEMORY_SCOPE_AGENT);
        ok = (v >= tgt);
      } while (!__all(ok));
      __builtin_amdgcn_sched_barrier(0);
    }

    const unsigned short* hsrc =
        (t == 0) ? (hinit + bh*16384) :
        (t == 1) ? (h1buf + bh*16384) :
                   (frag + ((long)(t-2)*2 + bh)*32768);

    // a-operand: 16 rows x K=1024, via L2-bypassing 8B atomic loads (issued up front)
    unsigned long long a64[64];
#pragma unroll
    for (int kb=0; kb<32; ++kb){
      const unsigned long long* p =
          (const unsigned long long*)&hsrc[hrow*1024 + kb*32 + g8];
      a64[2*kb+0] = __hip_atomic_load(&p[0], __ATOMIC_RELAXED, __HIP_MEMORY_SCOPE_AGENT);
      a64[2*kb+1] = __hip_atomic_load(&p[1], __ATOMIC_RELAXED, __HIP_MEMORY_SCOPE_AGENT);
    }

    floatx4 ac0 = (floatx4){0.f,0.f,0.f,0.f}, ac1 = ac0, ac2 = ac0, ac3 = ac0;
#pragma unroll
    for (int kb=0; kb<32; kb+=4){
#pragma unroll
      for (int j=0;j<4;++j){
        short8 bfr = *(const short8*)&Wrow[((kb+j)*32) ^ boff0];
        ull2 q; q.x = a64[2*(kb+j)]; q.y = a64[2*(kb+j)+1];
        short8 afr = __builtin_bit_cast(short8, q);
        if (j==0) ac0 = __builtin_amdgcn_mfma_f32_16x16x32_bf16(afr, bfr, ac0, 0, 0, 0);
        if (j==1) ac1 = __builtin_amdgcn_mfma_f32_16x16x32_bf16(afr, bfr, ac1, 0, 0, 0);
        if (j==2) ac2 = __builtin_amdgcn_mfma_f32_16x16x32_bf16(afr, bfr, ac2, 0, 0, 0);
        if (j==3) ac3 = __builtin_amdgcn_mfma_f32_16x16x32_bf16(afr, bfr, ac3, 0, 0, 0);
      }
    }
    floatx4 acc = (ac0 + ac1) + (ac2 + ac3);

    // epilogue -> LDS transpose tile (rows=batch, cols=wg-local feature)
#pragma unroll
    for (int i=0;i<4;++i){
      float s  = acc[i] + bf2f(wx[i]);
      float v  = fast_tanh(s);
      float aa = sigm(bf2f(al[i]));
      float hn = aa*hp[i] + (1.0f - aa)*v;
      tile[((lane>>4)*4 + i)*72 + w*16 + (lane&15)] = f2bf(hn);
      hp[i] = hn;
    }
    __syncthreads();   // tile complete

    // coalesced 8B atomic store of this wg's 16x64 h tile
    unsigned short* hdst = (t == 0) ? (h1buf + bh*16384)
                                    : (frag + ((long)(t-1)*2 + bh)*32768);
    {
      const int row  = tid >> 4;
      const int col4 = (tid & 15) * 4;
      unsigned long long v = *(const unsigned long long*)&tile[row*72 + col4];
      __hip_atomic_store((unsigned long long*)&hdst[row*1024 + base_r + col4], v,
                         __ATOMIC_RELAXED, __HIP_MEMORY_SCOPE_AGENT);
    }

    if (t + 1 < TT){
      __syncthreads();   // drains vmcnt(0): h stores acked at MALL; also guards tile reuse
      if (tid == 0)
        __hip_atomic_store(myflag, (unsigned)(t + 1),
                           __ATOMIC_RELAXED, __HIP_MEMORY_SCOPE_AGENT);
      // prefetch next step's alpha/wx while we spin (plain loads, pre_gemm data)
      fb = (((long)(t+1)*2 + bh)*128 + nt_a)*64 + lane;
      al = *(const ushort4v*)&frag[fb*4];
      wx = *(const ushort4v*)&frag[(fb + 64*64)*4];
    }
  }
}

// ---------------- expand bf16 h -> fp32 out/hout (memory-bound, off critical path)
__global__ __launch_bounds__(256) void out_writer(
    const unsigned short* __restrict__ frag,
    const unsigned short* __restrict__ h1buf,
    float* __restrict__ out, float* __restrict__ hout)
{
  const int t1 = blockIdx.z + 1;          // 1..1024
  const int bh = blockIdx.y;
  const int e  = (blockIdx.x*256 + threadIdx.x)*8;
  const int row = e >> 10, col = e & 1023;
  const unsigned short* src = (t1 == 1) ? (h1buf + bh*16384)
                                        : (frag + ((long)(t1-2)*2 + bh)*32768);
  short8 v = *(const short8*)&src[e];
  float o[8], hh[8];
#pragma unroll
  for (int j=0;j<8;++j){
    float h = bf2f((unsigned short)v[j]);
    float sg = sigm(h);
    hh[j] = h;
    o[j]  = h*h*sg;       // h * silu(h)
  }
  long ob = ((long)(t1-1)*BB + bh*16 + row)*DD + col;
  long hb = ((long)t1*BB + bh*16 + row)*DD + col;
  *(floatx4*)&out[ob]     = (floatx4){o[0],o[1],o[2],o[3]};
  *(floatx4*)&out[ob+4]   = (floatx4){o[4],o[5],o[6],o[7]};
  *(floatx4*)&hout[hb]    = (floatx4){hh[0],hh[1],hh[2],hh[3]};
  *(floatx4*)&hout[hb+4]  = (floatx4){hh[4],hh[5],hh[6],hh[7]};
}

extern "C" void kernel_launch(void* const* d_in, const int* in_sizes, int n_in,
                              void* d_out, int out_size, void* d_ws, size_t ws_size,
                              hipStream_t stream)
{
  const float* x  = (const float*)d_in[0];
  const float* h0 = (const float*)d_in[1];
  const float* Wa = (const float*)d_in[2];
  const float* ba = (const float*)d_in[3];
  const float* Wh = (const float*)d_in[4];
  const float* Wx = (const float*)d_in[5];
  const float* bx = (const float*)d_in[6];

  float* out  = (float*)d_out;                       // [T,B,D]
  float* hout = out + (long)TT*BB*DD;                // [T+1,B,D]

  uint8_t* ws = (uint8_t*)d_ws;
  unsigned short* frag  = (unsigned short*)(ws);
  unsigned short* Wcat  = (unsigned short*)(ws + WS_WCAT_OFF);
  unsigned short* hinit = (unsigned short*)(ws + WS_HINIT_OFF);
  unsigned short* h1buf = (unsigned short*)(ws + WS_H1_OFF);
  unsigned*       flags = (unsigned*)      (ws + WS_FLAG_OFF);

  init_kernel<<<8192, 256, 0, stream>>>(Wa, Wx, h0, hout, Wcat, hinit, flags);
  pre_gemm<<<dim3(16, 256), 256, 0, stream>>>(x, Wcat, ba, bx, frag);
  scan_kernel<<<32, 256, 0, stream>>>(Wh, h0, frag, hinit, h1buf, flags);
  out_writer<<<dim3(8, 2, 1024), 256, 0, stream>>>(frag, h1buf, out, hout);
}

// Round 4
// 5713.388 us; speedup vs baseline: 1.5534x; 1.5534x over previous
//
#include <hip/hip_runtime.h>
#include <hip/hip_bf16.h>
#include <stdint.h>

#define TT 1024
#define BB 32
#define DD 1024

typedef __attribute__((ext_vector_type(8))) short short8;
typedef __attribute__((ext_vector_type(4))) unsigned short ushort4v;
typedef __attribute__((ext_vector_type(4))) float floatx4;

static __device__ __forceinline__ unsigned short f2bf(float f){
  unsigned u = __float_as_uint(f);
  u += 0x7fffu + ((u >> 16) & 1u);   // RNE
  return (unsigned short)(u >> 16);
}
static __device__ __forceinline__ float bf2f(unsigned short s){
  return __uint_as_float(((unsigned)s) << 16);
}
static __device__ __forceinline__ float sigm(float x){
  return __fdividef(1.0f, 1.0f + __expf(-x));
}
static __device__ __forceinline__ float fast_tanh(float x){
  float e = __expf(2.0f * x);
  return 1.0f - __fdividef(2.0f, e + 1.0f);
}

// ---------------- workspace layout (bytes) ----------------
// frag: [t][bh(2)][nt(128)][lane(64)][4] bf16; nt 0..63 alpha preact, 64..127 wx.
// h_{t+1} is stored (relaxed agent atomics -> MALL, no L2 dirty lines) into the
// DEAD alpha half of frag[t-1]. Alpha preacts are ONLY ever read via atomic
// (L2-bypassing) loads, so no L2 ever caches those lines before the h store;
// the h reads at step t+1 are then PLAIN loads: guaranteed L2-miss -> fresh MALL
// data, and the fetched lines are shared by all 4 waves (and co-XCD wgs).
#define WS_FRAG_BYTES (134217728ull)                 // 1024*2*128*64*4*2
#define WS_WCAT_OFF   (WS_FRAG_BYTES)
#define WS_WCAT_BYTES (4194304ull)                   // 2048*1024*2 bf16 [Walpha;Wx]
#define WS_HINIT_OFF  (WS_WCAT_OFF + WS_WCAT_BYTES)  // 32*1024 bf16 h0
#define WS_H1_OFF     (WS_HINIT_OFF + 65536ull)      // 32*1024 bf16 h1
#define WS_FLAG_OFF   (WS_H1_OFF + 65536ull)         // 32 flags, 128B apart

// ---------------- init: cast weights, seed h0 bf16, write hout[0], zero flags
__global__ void init_kernel(const float* __restrict__ Wa, const float* __restrict__ Wx,
                            const float* __restrict__ h0, float* __restrict__ hout0,
                            unsigned short* __restrict__ Wcat,
                            unsigned short* __restrict__ hinit,
                            unsigned* __restrict__ flags)
{
  long i = (long)blockIdx.x * 256 + threadIdx.x;
  if (blockIdx.x == 0 && threadIdx.x < 32)
    __hip_atomic_store(&flags[threadIdx.x * 32], 0u, __ATOMIC_RELAXED, __HIP_MEMORY_SCOPE_AGENT);
  const long NW = 2048L * 1024L;
  for (long idx = i; idx < NW; idx += (long)gridDim.x * 256L){
    long r = idx >> 10, c = idx & 1023;
    float v = (r < 1024) ? Wa[r*1024 + c] : Wx[(r-1024)*1024 + c];
    Wcat[idx] = f2bf(v);
  }
  const long NH = 32L * 1024L;
  for (long idx = i; idx < NH; idx += (long)gridDim.x * 256L){
    float v = h0[idx];
    hinit[idx] = f2bf(v);
    hout0[idx] = v;          // hout[0] = h0 (fp32)
  }
}

// ---------------- precompute GEMM: [alpha_preact | wx] for all (t,b), bf16 MFMA-fragment layout
__global__ __launch_bounds__(256) void pre_gemm(
    const float* __restrict__ x, const unsigned short* __restrict__ Wcat,
    const float* __restrict__ b_alpha, const float* __restrict__ b_x,
    unsigned short* __restrict__ frag)
{
  __shared__ unsigned short A_lds[128*72];
  __shared__ unsigned short B_lds[128*72];
  const int tid = threadIdx.x;
  const int lane = tid & 63;
  const int w = tid >> 6;
  const int wm = w >> 1, wn = w & 1;
  const long m0 = (long)blockIdx.y * 128;
  const int n0 = blockIdx.x * 128;

  floatx4 acc[4][4];
#pragma unroll
  for (int i=0;i<4;++i)
#pragma unroll
    for (int j=0;j<4;++j) acc[i][j] = (floatx4){0.f,0.f,0.f,0.f};

  for (int kt=0; kt<16; ++kt){
    const int k0 = kt*64;
    __syncthreads();
#pragma unroll
    for (int rep=0; rep<4; ++rep){
      int flat = rep*2048 + tid*8;
      int r = flat >> 6, c = flat & 63;
      const float* src = &x[(m0 + r)*1024 + k0 + c];
      floatx4 f0 = *(const floatx4*)src;
      floatx4 f1 = *(const floatx4*)(src + 4);
      short8 v;
      v[0]=(short)f2bf(f0[0]); v[1]=(short)f2bf(f0[1]); v[2]=(short)f2bf(f0[2]); v[3]=(short)f2bf(f0[3]);
      v[4]=(short)f2bf(f1[0]); v[5]=(short)f2bf(f1[1]); v[6]=(short)f2bf(f1[2]); v[7]=(short)f2bf(f1[3]);
      *(short8*)&A_lds[r*72 + c] = v;
      short8 bv = *(const short8*)&Wcat[(long)(n0 + r)*1024 + k0 + c];
      *(short8*)&B_lds[r*72 + c] = bv;
    }
    __syncthreads();
#pragma unroll
    for (int kb=0; kb<2; ++kb){
      short8 a[4], b[4];
#pragma unroll
      for (int f=0; f<4; ++f)
        a[f] = *(const short8*)&A_lds[(wm*64 + f*16 + (lane&15))*72 + kb*32 + (lane>>4)*8];
#pragma unroll
      for (int f=0; f<4; ++f)
        b[f] = *(const short8*)&B_lds[(wn*64 + f*16 + (lane&15))*72 + kb*32 + (lane>>4)*8];
#pragma unroll
      for (int fm=0; fm<4; ++fm)
#pragma unroll
        for (int fn=0; fn<4; ++fn)
          acc[fm][fn] = __builtin_amdgcn_mfma_f32_16x16x32_bf16(a[fm], b[fn], acc[fm][fn], 0, 0, 0);
    }
  }

#pragma unroll
  for (int fm=0; fm<4; ++fm){
    const long mrow = m0 + wm*64 + fm*16;
    const int t  = (int)(mrow >> 5);
    const int bh = (int)((mrow >> 4) & 1);
#pragma unroll
    for (int fn=0; fn<4; ++fn){
      const int nf  = n0 + wn*64 + fn*16;
      const int nt  = nf >> 4;
      const int col = nf + (lane & 15);
      floatx4 v = acc[fm][fn];
      const float bias = (col < DD) ? b_alpha[col] : b_x[col - DD];
      ushort4v o;
#pragma unroll
      for (int i=0;i<4;++i) o[i] = f2bf(v[i] + bias);
      *(ushort4v*)&frag[((((long)t*2 + bh)*128 + nt)*64 + lane)*4] = o;
    }
  }
}

// ---------------- sequential scan (32 wgs = 2 groups x 16 slices)
// No fences anywhere. Cross-wg writes = relaxed agent atomics (MALL-direct).
// Cross-wg reads of h = PLAIN loads into guaranteed-virgin L2 lines (see frag
// comment). Ordering: __syncthreads drains vmcnt before the flag store;
// consumers' loads are pinned after the poll by the loop dependency + barrier
// + compiler memory clobbers.
__global__ __launch_bounds__(256, 1) void scan_kernel(
    const float* __restrict__ Wh, const float* __restrict__ h0,
    unsigned short* frag,                  // also h storage (dead alpha halves)
    const unsigned short* __restrict__ hinit,
    unsigned short* h1buf,
    unsigned* flags)
{
  __shared__ unsigned short W_lds[64*1024];  // XOR-swizzled, stride 1024
  const int tid  = threadIdx.x;
  const int lane = tid & 63;
  const int w    = tid >> 6;
  const int bh   = blockIdx.x & 1;
  const int wsld = blockIdx.x >> 1;     // 0..15 weight slice
  const int base_r = wsld * 64;

  // one-time: W_h slice fp32 -> bf16 LDS, 16B-granule XOR swizzle:
  // element (r,c) stored at r*1024 + (c ^ ((r&7)*8))  [shorts]
  for (int it=0; it<64; ++it){
    const int r = it, c = tid*4;
    floatx4 f = *(const floatx4*)&Wh[(long)(base_r + r)*1024 + c];
    ushort4v v;
    v[0]=f2bf(f[0]); v[1]=f2bf(f[1]); v[2]=f2bf(f[2]); v[3]=f2bf(f[3]);
    *(ushort4v*)&W_lds[r*1024 + (c ^ ((r&7)*8))] = v;
  }

  const int n0   = base_r + w*16;
  const int colf = n0 + (lane & 15);
  const int nt_a = n0 >> 4;
  float hp[4];
#pragma unroll
  for (int i=0;i<4;++i){
    int gb = bh*16 + (lane>>4)*4 + i;
    hp[i] = h0[(long)gb*1024 + colf];
  }
  __syncthreads();

  unsigned* myflag   = flags + (bh*16 + wsld)*32;
  unsigned* grpflags = flags + bh*16*32;
  const int hrow = lane & 15;
  const int g8   = (lane >> 4) * 8;
  const int brow = w*16 + (lane & 15);
  const int boff0 = g8 ^ ((brow & 7) * 8);
  const unsigned short* Wrow = &W_lds[brow * 1024];

  // preload frag for t=0: alpha via ATOMIC (never fill L2 with alpha-region lines),
  // wx via plain load (wx halves are never overwritten).
  long fb = (((long)0*2 + bh)*128 + nt_a)*64 + lane;
  unsigned long long a0 = __hip_atomic_load((const unsigned long long*)&frag[fb*4],
                                            __ATOMIC_RELAXED, __HIP_MEMORY_SCOPE_AGENT);
  ushort4v al = __builtin_bit_cast(ushort4v, a0);
  ushort4v wx = *(const ushort4v*)&frag[(fb + 64*64)*4];

  for (int t=0; t<TT; ++t){
    if (t > 0){
      const unsigned tgt = (unsigned)t;
      if (w == 0){
        for (;;){
          unsigned v = tgt;
          if (lane < 16)
            v = __hip_atomic_load(&grpflags[lane*32],
                                  __ATOMIC_RELAXED, __HIP_MEMORY_SCOPE_AGENT);
          if (__all(v >= tgt)) break;
          __builtin_amdgcn_s_sleep(1);
        }
      }
      __syncthreads();                  // release waves 1..3 after flag observed
      asm volatile("" ::: "memory");    // pin h loads below the poll
    }

    const unsigned short* hsrc =
        (t == 0) ? (hinit + bh*16384) :
        (t == 1) ? (h1buf + bh*16384) :
                   (frag + ((long)(t-2)*2 + bh)*32768);

    floatx4 ac0 = (floatx4){0.f,0.f,0.f,0.f}, ac1 = ac0, ac2 = ac0, ac3 = ac0;
#pragma unroll
    for (int kb=0; kb<32; kb+=4){
#pragma unroll
      for (int j=0;j<4;++j){
        short8 afr = *(const short8*)&hsrc[hrow*1024 + (kb+j)*32 + g8];  // plain: L2-shared
        short8 bfr = *(const short8*)&Wrow[((kb+j)*32) ^ boff0];
        if (j==0) ac0 = __builtin_amdgcn_mfma_f32_16x16x32_bf16(afr, bfr, ac0, 0, 0, 0);
        if (j==1) ac1 = __builtin_amdgcn_mfma_f32_16x16x32_bf16(afr, bfr, ac1, 0, 0, 0);
        if (j==2) ac2 = __builtin_amdgcn_mfma_f32_16x16x32_bf16(afr, bfr, ac2, 0, 0, 0);
        if (j==3) ac3 = __builtin_amdgcn_mfma_f32_16x16x32_bf16(afr, bfr, ac3, 0, 0, 0);
      }
    }
    floatx4 acc = (ac0 + ac1) + (ac2 + ac3);

    // epilogue: compute h_new, pack col-pairs via shuffle, 4B atomic stores (MALL)
    unsigned short* hdst = (t == 0) ? (h1buf + bh*16384)
                                    : (frag + ((long)(t-1)*2 + bh)*32768);
    const int  ceven = colf & ~1;
    const bool iseven = ((lane & 1) == 0);
#pragma unroll
    for (int i=0;i<4;++i){
      float s  = acc[i] + bf2f(wx[i]);
      float v  = fast_tanh(s);
      float aa = sigm(bf2f(al[i]));
      float hn = aa*hp[i] + (1.0f - aa)*v;
      hp[i] = hn;
      unsigned us    = (unsigned)f2bf(hn);
      unsigned other = (unsigned)__shfl_xor((int)us, 1, 64);
      if (iseven){
        unsigned pk = us | (other << 16);
        const int r = (lane>>4)*4 + i;
        __hip_atomic_store((unsigned*)&hdst[r*1024 + ceven], pk,
                           __ATOMIC_RELAXED, __HIP_MEMORY_SCOPE_AGENT);
      }
    }

    if (t + 1 < TT){
      __syncthreads();   // vmcnt(0) drain: all waves' h stores acked at MALL
      if (tid == 0)
        __hip_atomic_store(myflag, (unsigned)(t + 1),
                           __ATOMIC_RELAXED, __HIP_MEMORY_SCOPE_AGENT);
      // prefetch next step's alpha (atomic) / wx (plain) while we spin
      fb = (((long)(t+1)*2 + bh)*128 + nt_a)*64 + lane;
      unsigned long long av = __hip_atomic_load((const unsigned long long*)&frag[fb*4],
                                                __ATOMIC_RELAXED, __HIP_MEMORY_SCOPE_AGENT);
      al = __builtin_bit_cast(ushort4v, av);
      wx = *(const ushort4v*)&frag[(fb + 64*64)*4];
      asm volatile("" ::: "memory");    // pin prefetch issue before the poll
    }
  }
}

// ---------------- expand bf16 h -> fp32 out/hout (memory-bound, off critical path)
__global__ __launch_bounds__(256) void out_writer(
    const unsigned short* __restrict__ frag,
    const unsigned short* __restrict__ h1buf,
    float* __restrict__ out, float* __restrict__ hout)
{
  const int t1 = blockIdx.z + 1;          // 1..1024
  const int bh = blockIdx.y;
  const int e  = (blockIdx.x*256 + threadIdx.x)*8;
  const int row = e >> 10, col = e & 1023;
  const unsigned short* src = (t1 == 1) ? (h1buf + bh*16384)
                                        : (frag + ((long)(t1-2)*2 + bh)*32768);
  short8 v = *(const short8*)&src[e];
  float o[8], hh[8];
#pragma unroll
  for (int j=0;j<8;++j){
    float h = bf2f((unsigned short)v[j]);
    float sg = sigm(h);
    hh[j] = h;
    o[j]  = h*h*sg;       // h * silu(h)
  }
  long ob = ((long)(t1-1)*BB + bh*16 + row)*DD + col;
  long hb = ((long)t1*BB + bh*16 + row)*DD + col;
  *(floatx4*)&out[ob]     = (floatx4){o[0],o[1],o[2],o[3]};
  *(floatx4*)&out[ob+4]   = (floatx4){o[4],o[5],o[6],o[7]};
  *(floatx4*)&hout[hb]    = (floatx4){hh[0],hh[1],hh[2],hh[3]};
  *(floatx4*)&hout[hb+4]  = (floatx4){hh[4],hh[5],hh[6],hh[7]};
}

extern "C" void kernel_launch(void* const* d_in, const int* in_sizes, int n_in,
                              void* d_out, int out_size, void* d_ws, size_t ws_size,
                              hipStream_t stream)
{
  const float* x  = (const float*)d_in[0];
  const float* h0 = (const float*)d_in[1];
  const float* Wa = (const float*)d_in[2];
  const float* ba = (const float*)d_in[3];
  const float* Wh = (const float*)d_in[4];
  const float* Wx = (const float*)d_in[5];
  const float* bx = (const float*)d_in[6];

  float* out  = (float*)d_out;                       // [T,B,D]
  float* hout = out + (long)TT*BB*DD;                // [T+1,B,D]

  uint8_t* ws = (uint8_t*)d_ws;
  unsigned short* frag  = (unsigned short*)(ws);
  unsigned short* Wcat  = (unsigned short*)(ws + WS_WCAT_OFF);
  unsigned short* hinit = (unsigned short*)(ws + WS_HINIT_OFF);
  unsigned short* h1buf = (unsigned short*)(ws + WS_H1_OFF);
  unsigned*       flags = (unsigned*)      (ws + WS_FLAG_OFF);

  init_kernel<<<8192, 256, 0, stream>>>(Wa, Wx, h0, hout, Wcat, hinit, flags);
  pre_gemm<<<dim3(16, 256), 256, 0, stream>>>(x, Wcat, ba, bx, frag);
  scan_kernel<<<32, 256, 0, stream>>>(Wh, h0, frag, hinit, h1buf, flags);
  out_writer<<<dim3(8, 2, 1024), 256, 0, stream>>>(frag, h1buf, out, hout);
}